// Round 6
// baseline (488.216 us; speedup 1.0000x reference)
//
#include <hip/hip_runtime.h>
#include <stdint.h>

#define NN 50000
#define EE 1600000
#define IN_DIMC 256
#define HIDC 128
#define EPSC 1e-5f

// counting-sort geometry
#define NB 196        // coarse buckets: dst>>8, 256 nodes/bucket
#define GA 512        // phase-A blocks
#define CHUNK 3125    // EE / GA exactly

typedef unsigned short ushort_t;
typedef __attribute__((ext_vector_type(8))) short short8;
typedef __attribute__((ext_vector_type(4))) float floatx4;

static __device__ inline ushort_t f2bf(float f) {
    unsigned int u = __float_as_uint(f);
    u = u + 0x7fffu + ((u >> 16) & 1u);   // RNE
    return (ushort_t)(u >> 16);
}
static __device__ inline unsigned int pack2(float a, float b) {
    return (unsigned int)f2bf(a) | ((unsigned int)f2bf(b) << 16);
}
static __device__ inline float bf2f(unsigned int bits16) {
    return __uint_as_float(bits16 << 16);
}

// ---------------------------------------------------------------------------
// Weight transpose + bf16 convert, 4 segments in one launch.
// Wt[n][k] = bf16(W[k][n]); W is [K][128].
// seg0: W_in (K=256, 32768); seg1..3: W_hid, Wl1, Wr1 (K=128, 16384 each).
// (Wl2/Wr2 are produced by fold_kernel with BN3 folded in.)
// ---------------------------------------------------------------------------
__global__ __launch_bounds__(256) void tcvt_all_kernel(
    const float* __restrict__ W_in, const float* __restrict__ W_hid,
    const float* __restrict__ Wl1, const float* __restrict__ Wr1,
    ushort_t* __restrict__ Wt_in, ushort_t* __restrict__ Wt_hid,
    ushort_t* __restrict__ Wtl1, ushort_t* __restrict__ Wtr1)
{
    const int idx = blockIdx.x * 256 + threadIdx.x;
    if (idx < 32768) {
        const int n = idx >> 8;
        const int k = idx & 255;
        Wt_in[idx] = f2bf(W_in[(size_t)k * 128 + n]);
    } else if (idx < 32768 + 3 * 16384) {
        const int r = idx - 32768;
        const int seg = r / 16384;
        const int j = r - seg * 16384;
        const int n = j >> 7;
        const int k = j & 127;
        const float* W; ushort_t* Wt;
        switch (seg) {
            case 0: W = W_hid; Wt = Wt_hid; break;
            case 1: W = Wl1;  Wt = Wtl1;  break;
            default: W = Wr1; Wt = Wtr1;  break;
        }
        Wt[j] = f2bf(W[(size_t)k * 128 + n]);
    }
}

// ---------------------------------------------------------------------------
// Fold BN3 into stage-4 weights (bf16-transposed) + bias:
//   a[k]=g/sqrt(var+eps); b[k]=be-mean*a
//   Wt*f[n*128+k] = bf16(a[k]*W[k][n]);  bf[n] = bl[n]+sum_k b[k]*(Wl+Wr)[k][n]
// ---------------------------------------------------------------------------
__global__ __launch_bounds__(256) void fold_kernel(
    const float* __restrict__ stats, const float* __restrict__ g,
    const float* __restrict__ be, const float* __restrict__ Wl,
    const float* __restrict__ Wr, const float* __restrict__ bl,
    ushort_t* __restrict__ Wtlf, ushort_t* __restrict__ Wtrf,
    float* __restrict__ bf)
{
    __shared__ float a[128], b[128];
    const int t = threadIdx.x;
    if (t < 128) {
        const float invM = 1.0f / (float)NN;
        const float mean = stats[t] * invM;
        float var = stats[128 + t] * invM - mean * mean;
        if (var < 0.0f) var = 0.0f;
        const float s = g[t] / sqrtf(var + EPSC);
        a[t] = s;
        b[t] = be[t] - mean * s;
    }
    __syncthreads();
    const int idx = blockIdx.x * 256 + t;   // grid 64 -> 16384 exactly
    {
        const int n = idx >> 7;
        const int k = idx & 127;
        Wtlf[idx] = f2bf(a[k] * Wl[(size_t)k * 128 + n]);
        Wtrf[idx] = f2bf(a[k] * Wr[(size_t)k * 128 + n]);
    }
    if (blockIdx.x == 0 && t < 128) {
        float s = bl[t];
        for (int k = 0; k < 128; k++)
            s += b[k] * (Wl[k * 128 + t] + Wr[k * 128 + t]);
        bf[t] = s;
    }
}

// ---------------------------------------------------------------------------
// MFMA GEMM (dense stages 1-2): C[M,128] = A@W + bias, fp32 A input,
// optional BN-affine+relu on A-load; fused column stats. (verified r3-r5)
// ---------------------------------------------------------------------------
__global__ __launch_bounds__(256) void mfma_gemm_kernel(
    const float* __restrict__ A1, const ushort_t* __restrict__ Wt1, int K1,
    const float* __restrict__ bias, float* __restrict__ C, int M,
    const float* __restrict__ preStats, const float* __restrict__ preG,
    const float* __restrict__ preBe, float* __restrict__ outStats)
{
    __shared__ ushort_t As[64 * 72];
    __shared__ ushort_t Bs[128 * 72];
    __shared__ float aArr[128], bArr[128];
    __shared__ float red_s[4][64], red_q[4][64];

    const int t     = threadIdx.x;
    const int lane  = t & 63;
    const int wave  = t >> 6;
    const int quad  = lane >> 4;
    const int l15   = lane & 15;
    const int mhalf = wave & 1;
    const int nhalf = wave >> 1;
    const int row0  = blockIdx.x * 64;
    const int doAffine = (preStats != nullptr);

    if (doAffine && t < 128) {
        const float invM = 1.0f / (float)M;
        const float mean = preStats[t] * invM;
        float var = preStats[128 + t] * invM - mean * mean;
        if (var < 0.0f) var = 0.0f;
        const float s = preG[t] / sqrtf(var + EPSC);
        aArr[t] = s;
        bArr[t] = preBe[t] - mean * s;
    }
    if (doAffine) __syncthreads();

    floatx4 acc[2][4];
    #pragma unroll
    for (int i = 0; i < 2; i++)
        #pragma unroll
        for (int j = 0; j < 4; j++)
            acc[i][j] = (floatx4){0.0f, 0.0f, 0.0f, 0.0f};

    const int K = K1;
    for (int kc = 0; kc < K; kc += 64) {
        #pragma unroll
        for (int p = 0; p < 2; p++) {
            const int idx = p * 256 + t;
            const int r   = idx >> 3;
            const int c0  = (idx & 7) * 8;
            int gr = row0 + r;
            if (gr > M - 1) gr = M - 1;
            const size_t base = (size_t)gr * K + kc + c0;
            float4 v0 = *(const float4*)(A1 + base);
            float4 v1 = *(const float4*)(A1 + base + 4);
            if (doAffine) {
                const int k0 = kc + c0;
                v0.x = fmaxf(aArr[k0]     * v0.x + bArr[k0],     0.0f);
                v0.y = fmaxf(aArr[k0 + 1] * v0.y + bArr[k0 + 1], 0.0f);
                v0.z = fmaxf(aArr[k0 + 2] * v0.z + bArr[k0 + 2], 0.0f);
                v0.w = fmaxf(aArr[k0 + 3] * v0.w + bArr[k0 + 3], 0.0f);
                v1.x = fmaxf(aArr[k0 + 4] * v1.x + bArr[k0 + 4], 0.0f);
                v1.y = fmaxf(aArr[k0 + 5] * v1.y + bArr[k0 + 5], 0.0f);
                v1.z = fmaxf(aArr[k0 + 6] * v1.z + bArr[k0 + 6], 0.0f);
                v1.w = fmaxf(aArr[k0 + 7] * v1.w + bArr[k0 + 7], 0.0f);
            }
            uint4 w;
            w.x = pack2(v0.x, v0.y);
            w.y = pack2(v0.z, v0.w);
            w.z = pack2(v1.x, v1.y);
            w.w = pack2(v1.z, v1.w);
            *(uint4*)(As + r * 72 + c0) = w;
        }
        #pragma unroll
        for (int p = 0; p < 4; p++) {
            const int idx = p * 256 + t;
            const int n   = idx >> 3;
            const int c0  = (idx & 7) * 8;
            *(uint4*)(Bs + n * 72 + c0) =
                *(const uint4*)(Wt1 + (size_t)n * K + kc + c0);
        }
        __syncthreads();

        #pragma unroll
        for (int ks = 0; ks < 2; ks++) {
            const int ko = ks * 32 + quad * 8;
            const short8 a0 = *(const short8*)(As + (mhalf * 32 + l15) * 72 + ko);
            const short8 a1 = *(const short8*)(As + (mhalf * 32 + 16 + l15) * 72 + ko);
            short8 b[4];
            #pragma unroll
            for (int j = 0; j < 4; j++)
                b[j] = *(const short8*)(Bs + (nhalf * 64 + j * 16 + l15) * 72 + ko);
            #pragma unroll
            for (int j = 0; j < 4; j++) {
                acc[0][j] = __builtin_amdgcn_mfma_f32_16x16x32_bf16(a0, b[j], acc[0][j], 0, 0, 0);
                acc[1][j] = __builtin_amdgcn_mfma_f32_16x16x32_bf16(a1, b[j], acc[1][j], 0, 0, 0);
            }
        }
        __syncthreads();
    }

    float s_[4], q_[4];
    #pragma unroll
    for (int j = 0; j < 4; j++) { s_[j] = 0.0f; q_[j] = 0.0f; }
    #pragma unroll
    for (int j = 0; j < 4; j++) {
        const int col = nhalf * 64 + j * 16 + l15;
        const float bv = bias[col];
        #pragma unroll
        for (int i = 0; i < 2; i++) {
            const int rbase = row0 + mhalf * 32 + i * 16 + quad * 4;
            #pragma unroll
            for (int reg = 0; reg < 4; reg++) {
                const float val = acc[i][j][reg] + bv;
                const int r_ = rbase + reg;
                if (r_ < M) {
                    C[(size_t)r_ * HIDC + col] = val;
                    s_[j] += val;
                    q_[j] += val * val;
                }
            }
        }
    }
    #pragma unroll
    for (int j = 0; j < 4; j++) {
        s_[j] += __shfl_xor(s_[j], 16, 64);
        s_[j] += __shfl_xor(s_[j], 32, 64);
        q_[j] += __shfl_xor(q_[j], 16, 64);
        q_[j] += __shfl_xor(q_[j], 32, 64);
    }
    if (quad == 0) {
        #pragma unroll
        for (int j = 0; j < 4; j++) {
            red_s[wave][j * 16 + l15] = s_[j];
            red_q[wave][j * 16 + l15] = q_[j];
        }
    }
    __syncthreads();
    if (t < 128) {
        const int g = t >> 6;
        const int cc = t & 63;
        atomicAdd(&outStats[t],       red_s[g * 2][cc] + red_s[g * 2 + 1][cc]);
        atomicAdd(&outStats[128 + t], red_q[g * 2][cc] + red_q[g * 2 + 1][cc]);
    }
}

// ---------------------------------------------------------------------------
// Fused SAGE GEMM: per 64-row block, mean-gather neighbors straight into the
// A-tile LDS (wave=16 nodes, 2 cols/lane, 8 gathers in flight), then the dual
// GEMM  C = mean@Wtl + F@Wtr + bias.  Outputs optional fp32 and/or bf16 C,
// fused column stats.
// ---------------------------------------------------------------------------
__global__ __launch_bounds__(256) void sage_gemm_kernel(
    const ushort_t* __restrict__ F,          // [NN][128] bf16 gather src + right path
    const int* __restrict__ rowp, const int* __restrict__ colIdx,
    const ushort_t* __restrict__ Wtl, const ushort_t* __restrict__ Wtr,
    const float* __restrict__ bias,
    float* __restrict__ Cf, ushort_t* __restrict__ Cb,
    float* __restrict__ outStats)
{
    __shared__ ushort_t AsG[2 * 64 * 72];   // gathered mean tile, both k-chunks
    __shared__ ushort_t Bs[128 * 72];
    __shared__ float red_s[4][64], red_q[4][64];

    const int t     = threadIdx.x;
    const int lane  = t & 63;
    const int wave  = t >> 6;
    const int quad  = lane >> 4;
    const int l15   = lane & 15;
    const int mhalf = wave & 1;
    const int nhalf = wave >> 1;
    const int row0  = blockIdx.x * 64;

    // ---- Phase G: mean-gather
    const int coff   = lane * 2;
    const int chunk  = lane >> 5;
    const int klocal = (lane * 2) & 63;
    for (int i = 0; i < 16; i++) {
        const int r = wave * 16 + i;
        int gn = row0 + r; if (gn > NN - 1) gn = NN - 1;
        const int b = __builtin_amdgcn_readfirstlane(rowp[gn]);
        const int e = __builtin_amdgcn_readfirstlane(rowp[gn + 1]);
        float ax = 0.0f, ay = 0.0f;
        int j = b;
        for (; j + 8 <= e; j += 8) {
            const int s0 = colIdx[j + 0];
            const int s1 = colIdx[j + 1];
            const int s2 = colIdx[j + 2];
            const int s3 = colIdx[j + 3];
            const int s4 = colIdx[j + 4];
            const int s5 = colIdx[j + 5];
            const int s6 = colIdx[j + 6];
            const int s7 = colIdx[j + 7];
            const unsigned int v0 = *(const unsigned int*)(F + (size_t)s0 * HIDC + coff);
            const unsigned int v1 = *(const unsigned int*)(F + (size_t)s1 * HIDC + coff);
            const unsigned int v2 = *(const unsigned int*)(F + (size_t)s2 * HIDC + coff);
            const unsigned int v3 = *(const unsigned int*)(F + (size_t)s3 * HIDC + coff);
            const unsigned int v4 = *(const unsigned int*)(F + (size_t)s4 * HIDC + coff);
            const unsigned int v5 = *(const unsigned int*)(F + (size_t)s5 * HIDC + coff);
            const unsigned int v6 = *(const unsigned int*)(F + (size_t)s6 * HIDC + coff);
            const unsigned int v7 = *(const unsigned int*)(F + (size_t)s7 * HIDC + coff);
            ax += bf2f(v0 & 0xffffu) + bf2f(v1 & 0xffffu) + bf2f(v2 & 0xffffu)
                + bf2f(v3 & 0xffffu) + bf2f(v4 & 0xffffu) + bf2f(v5 & 0xffffu)
                + bf2f(v6 & 0xffffu) + bf2f(v7 & 0xffffu);
            ay += bf2f(v0 >> 16) + bf2f(v1 >> 16) + bf2f(v2 >> 16)
                + bf2f(v3 >> 16) + bf2f(v4 >> 16) + bf2f(v5 >> 16)
                + bf2f(v6 >> 16) + bf2f(v7 >> 16);
        }
        for (; j < e; j++) {
            const int s = colIdx[j];
            const unsigned int v = *(const unsigned int*)(F + (size_t)s * HIDC + coff);
            ax += bf2f(v & 0xffffu);
            ay += bf2f(v >> 16);
        }
        const int dg = e - b;
        const float inv = 1.0f / (float)(dg > 1 ? dg : 1);
        *(unsigned int*)(AsG + chunk * 4608 + r * 72 + klocal) = pack2(ax * inv, ay * inv);
    }
    __syncthreads();

    floatx4 acc[2][4];
    #pragma unroll
    for (int i = 0; i < 2; i++)
        #pragma unroll
        for (int j = 0; j < 4; j++)
            acc[i][j] = (floatx4){0.0f, 0.0f, 0.0f, 0.0f};

    for (int s = 0; s < 2; s++) {
        const ushort_t* Wt = s ? Wtr : Wtl;
        for (int kcI = 0; kcI < 2; kcI++) {
            if (s == 1) {
                // stage right-path A = F rows (reuses AsG chunk-0 region;
                // prior barrier guarantees all reads of it are done)
                #pragma unroll
                for (int p = 0; p < 2; p++) {
                    const int idx = p * 256 + t;
                    const int r  = idx >> 3;
                    const int c0 = (idx & 7) * 8;
                    int gr = row0 + r; if (gr > NN - 1) gr = NN - 1;
                    *(uint4*)(AsG + r * 72 + c0) =
                        *(const uint4*)(F + (size_t)gr * HIDC + kcI * 64 + c0);
                }
            }
            #pragma unroll
            for (int p = 0; p < 4; p++) {
                const int idx = p * 256 + t;
                const int n  = idx >> 3;
                const int c0 = (idx & 7) * 8;
                *(uint4*)(Bs + n * 72 + c0) =
                    *(const uint4*)(Wt + (size_t)n * HIDC + kcI * 64 + c0);
            }
            __syncthreads();

            const ushort_t* Ab = (s == 0) ? (AsG + kcI * 4608) : AsG;
            #pragma unroll
            for (int ks = 0; ks < 2; ks++) {
                const int ko = ks * 32 + quad * 8;
                const short8 a0 = *(const short8*)(Ab + (mhalf * 32 + l15) * 72 + ko);
                const short8 a1 = *(const short8*)(Ab + (mhalf * 32 + 16 + l15) * 72 + ko);
                short8 b[4];
                #pragma unroll
                for (int j = 0; j < 4; j++)
                    b[j] = *(const short8*)(Bs + (nhalf * 64 + j * 16 + l15) * 72 + ko);
                #pragma unroll
                for (int j = 0; j < 4; j++) {
                    acc[0][j] = __builtin_amdgcn_mfma_f32_16x16x32_bf16(a0, b[j], acc[0][j], 0, 0, 0);
                    acc[1][j] = __builtin_amdgcn_mfma_f32_16x16x32_bf16(a1, b[j], acc[1][j], 0, 0, 0);
                }
            }
            __syncthreads();
        }
    }

    float s_[4], q_[4];
    #pragma unroll
    for (int j = 0; j < 4; j++) { s_[j] = 0.0f; q_[j] = 0.0f; }
    #pragma unroll
    for (int j = 0; j < 4; j++) {
        const int col = nhalf * 64 + j * 16 + l15;
        const float bv = bias[col];
        #pragma unroll
        for (int i = 0; i < 2; i++) {
            const int rbase = row0 + mhalf * 32 + i * 16 + quad * 4;
            #pragma unroll
            for (int reg = 0; reg < 4; reg++) {
                const float val = acc[i][j][reg] + bv;
                const int r_ = rbase + reg;
                if (r_ < NN) {
                    if (Cf) Cf[(size_t)r_ * HIDC + col] = val;
                    if (Cb) Cb[(size_t)r_ * HIDC + col] = f2bf(val);
                    s_[j] += val;
                    q_[j] += val * val;
                }
            }
        }
    }
    #pragma unroll
    for (int j = 0; j < 4; j++) {
        s_[j] += __shfl_xor(s_[j], 16, 64);
        s_[j] += __shfl_xor(s_[j], 32, 64);
        q_[j] += __shfl_xor(q_[j], 16, 64);
        q_[j] += __shfl_xor(q_[j], 32, 64);
    }
    if (quad == 0) {
        #pragma unroll
        for (int j = 0; j < 4; j++) {
            red_s[wave][j * 16 + l15] = s_[j];
            red_q[wave][j * 16 + l15] = q_[j];
        }
    }
    __syncthreads();
    if (t < 128) {
        const int g = t >> 6;
        const int cc = t & 63;
        atomicAdd(&outStats[t],       red_s[g * 2][cc] + red_s[g * 2 + 1][cc]);
        atomicAdd(&outStats[128 + t], red_q[g * 2][cc] + red_q[g * 2 + 1][cc]);
    }
}

// ---------------------------------------------------------------------------
// BN apply: dst fp32 (optional) and/or dst bf16 (optional), + optional relu
// ---------------------------------------------------------------------------
__global__ __launch_bounds__(256) void bn_apply_kernel(
    const float* __restrict__ src, float* __restrict__ dstF,
    ushort_t* __restrict__ dstB, const float* __restrict__ stats,
    const float* __restrict__ gamma, const float* __restrict__ beta,
    int relu, int M)
{
    __shared__ float sc[128], sh[128];
    const int t = threadIdx.x;
    if (t < 128) {
        const float invM = 1.0f / (float)M;
        const float mean = stats[t] * invM;
        float var = stats[128 + t] * invM - mean * mean;
        if (var < 0.0f) var = 0.0f;
        const float s = gamma[t] / sqrtf(var + EPSC);
        sc[t] = s;
        sh[t] = beta[t] - mean * s;
    }
    __syncthreads();

    const int total4 = M * HIDC / 4;
    for (int i = blockIdx.x * 256 + t; i < total4; i += gridDim.x * 256) {
        float4 v = ((const float4*)src)[i];
        const int c = (i * 4) & 127;
        v.x = v.x * sc[c]     + sh[c];
        v.y = v.y * sc[c + 1] + sh[c + 1];
        v.z = v.z * sc[c + 2] + sh[c + 2];
        v.w = v.w * sc[c + 3] + sh[c + 3];
        if (relu) {
            v.x = fmaxf(v.x, 0.0f); v.y = fmaxf(v.y, 0.0f);
            v.z = fmaxf(v.z, 0.0f); v.w = fmaxf(v.w, 0.0f);
        }
        if (dstF) ((float4*)dstF)[i] = v;
        if (dstB) {
            uint2 w;
            w.x = pack2(v.x, v.y);
            w.y = pack2(v.z, v.w);
            *(uint2*)(dstB + (size_t)i * 4) = w;
        }
    }
}

// ---------------------------------------------------------------------------
// CSR build — atomic-free two-level counting sort. ebuf packs (src<<8)|(dst&255)
// (src < 2^16 wait no — src < 50000 < 2^16? 50000 < 65536 yes; fits 24 bits).
// ---------------------------------------------------------------------------
__global__ __launch_bounds__(256) void bucket_hist_kernel(
    const int* __restrict__ dstArr, int* __restrict__ hist2D)
{
    __shared__ int hist[NB];
    const int t = threadIdx.x;
    for (int i = t; i < NB; i += 256) hist[i] = 0;
    __syncthreads();
    const int e0 = blockIdx.x * CHUNK;
    const int e1 = e0 + CHUNK;
    for (int e = e0 + t; e < e1; e += 256)
        atomicAdd(&hist[dstArr[e] >> 8], 1);
    __syncthreads();
    for (int i = t; i < NB; i += 256)
        hist2D[(size_t)i * GA + blockIdx.x] = hist[i];
}

__global__ __launch_bounds__(256) void bucket_offsets_kernel(
    int* __restrict__ hist2D, int* __restrict__ bucketBase, int* __restrict__ rowp)
{
    __shared__ int wtot[4];
    const int t = threadIdx.x;
    int tot = 0;
    if (t < NB) {
        int4* p = (int4*)(hist2D + (size_t)t * GA);
        int s = 0;
        for (int i = 0; i < GA / 4; i++) {
            int4 h = p[i];
            int4 o;
            o.x = s; s += h.x;
            o.y = s; s += h.y;
            o.z = s; s += h.z;
            o.w = s; s += h.w;
            p[i] = o;
        }
        tot = s;
    }
    const int lane = t & 63, w = t >> 6;
    int x = tot;
    #pragma unroll
    for (int off = 1; off < 64; off <<= 1) {
        const int y = __shfl_up(x, off);
        if (lane >= off) x += y;
    }
    if (lane == 63) wtot[w] = x;
    __syncthreads();
    int woff = 0;
    #pragma unroll
    for (int j = 0; j < 4; j++) if (j < w) woff += wtot[j];
    const int excl = x + woff - tot;
    if (t < NB) bucketBase[t] = excl;
    if (t == 0) { bucketBase[NB] = EE; rowp[NN] = EE; }
}

__global__ __launch_bounds__(256) void bucket_scatter_kernel(
    const int* __restrict__ srcArr, const int* __restrict__ dstArr,
    const int* __restrict__ hist2D, const int* __restrict__ bucketBase,
    int* __restrict__ ebuf)
{
    __shared__ int cur[NB];
    const int t = threadIdx.x;
    for (int i = t; i < NB; i += 256)
        cur[i] = bucketBase[i] + hist2D[(size_t)i * GA + blockIdx.x];
    __syncthreads();
    const int e0 = blockIdx.x * CHUNK;
    const int e1 = e0 + CHUNK;
    for (int e = e0 + t; e < e1; e += 256) {
        const int d = dstArr[e];
        const int s = srcArr[e];
        const int p = atomicAdd(&cur[d >> 8], 1);
        ebuf[p] = (s << 8) | (d & 255);
    }
}

__global__ __launch_bounds__(256) void fine_sort_kernel(
    const int* __restrict__ ebuf, const int* __restrict__ bucketBase,
    int* __restrict__ rowp, int* __restrict__ col)
{
    __shared__ int cnt[256];
    __shared__ int wtot[4];
    const int b = blockIdx.x;
    const int t = threadIdx.x;
    const int bb0 = bucketBase[b];
    const int bb1 = bucketBase[b + 1];
    cnt[t] = 0;
    __syncthreads();
    for (int e = bb0 + t; e < bb1; e += 256)
        atomicAdd(&cnt[ebuf[e] & 255], 1);
    __syncthreads();
    const int lane = t & 63, w = t >> 6;
    const int v = cnt[t];
    int x = v;
    #pragma unroll
    for (int off = 1; off < 64; off <<= 1) {
        const int y = __shfl_up(x, off);
        if (lane >= off) x += y;
    }
    if (lane == 63) wtot[w] = x;
    __syncthreads();
    int woff = 0;
    #pragma unroll
    for (int j = 0; j < 4; j++) if (j < w) woff += wtot[j];
    const int excl = x + woff - v;
    const int node = b * 256 + t;
    if (node < NN) rowp[node] = bb0 + excl;
    __syncthreads();
    cnt[t] = excl;
    __syncthreads();
    for (int e = bb0 + t; e < bb1; e += 256) {
        const int sd = ebuf[e];
        const int p = atomicAdd(&cnt[sd & 255], 1);
        col[bb0 + p] = (unsigned)sd >> 8;
    }
}

// ---------------------------------------------------------------------------
extern "C" void kernel_launch(void* const* d_in, const int* in_sizes, int n_in,
                              void* d_out, int out_size, void* d_ws, size_t ws_size,
                              hipStream_t stream)
{
    const float* x     = (const float*)d_in[0];
    const int*   ei    = (const int*)  d_in[1];
    const float* W_in  = (const float*)d_in[2];
    const float* b_in  = (const float*)d_in[3];
    const float* g1    = (const float*)d_in[4];
    const float* be1   = (const float*)d_in[5];
    const float* W_hid = (const float*)d_in[6];
    const float* b_hid = (const float*)d_in[7];
    const float* g2    = (const float*)d_in[8];
    const float* be2   = (const float*)d_in[9];
    const float* Wl1   = (const float*)d_in[10];
    const float* bl1   = (const float*)d_in[11];
    const float* Wr1   = (const float*)d_in[12];
    const float* g3    = (const float*)d_in[13];
    const float* be3   = (const float*)d_in[14];
    const float* Wl2   = (const float*)d_in[15];
    const float* bl2   = (const float*)d_in[16];
    const float* Wr2   = (const float*)d_in[17];
    const float* g4    = (const float*)d_in[18];
    const float* be4   = (const float*)d_in[19];

    const int* srcArr = ei;        // edge_index[0]
    const int* dstArr = ei + EE;   // edge_index[1]

    char* ws = (char*)d_ws;
    float*    bufA      = (float*)ws;    ws += (size_t)NN * HIDC * sizeof(float);
    float*    bufB      = (float*)ws;    ws += (size_t)NN * HIDC * sizeof(float);
    ushort_t* featB16   = (ushort_t*)ws; ws += (size_t)NN * HIDC * sizeof(ushort_t);
    ushort_t* o3B16     = (ushort_t*)ws; ws += (size_t)NN * HIDC * sizeof(ushort_t);
    float*    stats     = (float*)ws;    ws += 4 * 256 * sizeof(float);
    int*      hist2D    = (int*)ws;      ws += (size_t)NB * GA * sizeof(int);
    int*      bucketBase= (int*)ws;      ws += (NB + 4) * sizeof(int);
    int*      rowp      = (int*)ws;      ws += (size_t)(NN + 4) * sizeof(int);
    int*      colIdx    = (int*)ws;      ws += (size_t)EE * sizeof(int);
    int*      ebuf      = (int*)ws;      ws += (size_t)EE * sizeof(int);
    ushort_t* Wt_in     = (ushort_t*)ws; ws += 128 * 256 * sizeof(ushort_t);
    ushort_t* Wt_hid    = (ushort_t*)ws; ws += 128 * 128 * sizeof(ushort_t);
    ushort_t* Wtl1      = (ushort_t*)ws; ws += 128 * 128 * sizeof(ushort_t);
    ushort_t* Wtr1      = (ushort_t*)ws; ws += 128 * 128 * sizeof(ushort_t);
    ushort_t* Wtl2f     = (ushort_t*)ws; ws += 128 * 128 * sizeof(ushort_t);
    ushort_t* Wtr2f     = (ushort_t*)ws; ws += 128 * 128 * sizeof(ushort_t);
    float*    bf2       = (float*)ws;    ws += 128 * sizeof(float);

    float* out0 = (float*)d_out;             // feat  [NN*HID] fp32
    float* out1 = out0 + (size_t)NN * HIDC;  // out   [NN*HID] fp32

    // zero stats only
    hipMemsetAsync(stats, 0, 4 * 256 * sizeof(float), stream);

    // weight transpose + bf16 convert (4 segments, one launch)
    tcvt_all_kernel<<<320, 256, 0, stream>>>(W_in, W_hid, Wl1, Wr1,
                                             Wt_in, Wt_hid, Wtl1, Wtr1);

    // CSR build — atomic-free counting sort
    bucket_hist_kernel<<<GA, 256, 0, stream>>>(dstArr, hist2D);
    bucket_offsets_kernel<<<1, 256, 0, stream>>>(hist2D, bucketBase, rowp);
    bucket_scatter_kernel<<<GA, 256, 0, stream>>>(srcArr, dstArr, hist2D,
                                                  bucketBase, ebuf);
    fine_sort_kernel<<<NB, 256, 0, stream>>>(ebuf, bucketBase, rowp, colIdx);

    const int gemmGrid = (NN + 63) / 64;   // 782

    // stage 1: input linear (x fp32, K=256) -> bufA fp32 + stats0
    mfma_gemm_kernel<<<gemmGrid, 256, 0, stream>>>(
        x, Wt_in, IN_DIMC, b_in, bufA, NN,
        nullptr, nullptr, nullptr, stats + 0);

    // stage 2: hidden linear, BN1+relu fused on A-load -> bufB fp32 + stats1
    mfma_gemm_kernel<<<gemmGrid, 256, 0, stream>>>(
        bufA, Wt_hid, HIDC, b_hid, bufB, NN,
        stats + 0, g1, be1, stats + 256);

    // BN2+relu -> out0 (fp32) + featB16 (bf16)
    bn_apply_kernel<<<1024, 256, 0, stream>>>(bufB, out0, featB16,
                                              stats + 256, g2, be2, 1, NN);

    // stage 3: fused SAGE1 (gather + dual GEMM) -> o3B16 raw + stats2
    sage_gemm_kernel<<<gemmGrid, 256, 0, stream>>>(
        featB16, rowp, colIdx, Wtl1, Wtr1, bl1,
        nullptr, o3B16, stats + 512);

    // fold BN3 into stage-4 weights (bf16-transposed) + bias
    fold_kernel<<<64, 256, 0, stream>>>(stats + 512, g3, be3, Wl2, Wr2, bl2,
                                        Wtl2f, Wtr2f, bf2);

    // stage 4: fused SAGE2 on raw o3 (BN3 folded) -> bufB fp32 + stats3
    sage_gemm_kernel<<<gemmGrid, 256, 0, stream>>>(
        o3B16, rowp, colIdx, Wtl2f, Wtr2f, bf2,
        bufB, nullptr, stats + 768);

    // BN4 -> out1 (fp32)
    bn_apply_kernel<<<1024, 256, 0, stream>>>(bufB, out1, nullptr,
                                              stats + 768, g4, be4, 0, NN);
}